// Round 7
// baseline (5349.375 us; speedup 1.0000x reference)
//
#include <hip/hip_runtime.h>

#define HDIM 256
#define TLEN 2048
#define SELEN 64
#define MSZ 8

typedef _Float16 f16x2 __attribute__((ext_vector_type(2)));
typedef unsigned int u32x16 __attribute__((ext_vector_type(16)));

__device__ __forceinline__ float dot2f(unsigned int w, unsigned int h, float acc) {
  return __builtin_amdgcn_fdot2(__builtin_bit_cast(f16x2, w),
                                __builtin_bit_cast(f16x2, h), acc, false);
}

__device__ __forceinline__ unsigned int pack2(float a, float b) {
  f16x2 v;
  v.x = (_Float16)a; v.y = (_Float16)b;
  return __builtin_bit_cast(unsigned int, v);
}

__device__ __forceinline__ float uni(float v) {  // force to SGPR
  return __builtin_bit_cast(float, __builtin_amdgcn_readfirstlane(__builtin_bit_cast(int, v)));
}

__device__ __forceinline__ float sigm(float x)   { return 1.0f / (1.0f + __expf(-x)); }
__device__ __forceinline__ float tanh_f(float x) { return 1.0f - 2.0f / (__expf(2.0f * x) + 1.0f); }

// LDS layout (bytes)
#define WO_OFF    0        // 8192 uint4           = 131072 B (o-gate fp16x2 weights)
#define WIH_OFF   131072   // 1024 rows * float4   = 16384 B  (input-proj weights, padded)
#define BIAS_OFF  147456   // 256 * float4         = 4096 B   (combined biases, 4 gates)
#define CNT_OFF   151552   // 2048 * u8            = 2048 B   (window cover counts)
#define H2_OFF    153600   // 2 bufs * 4*144 B     = 1152 B   (h fp16, quarters padded +16B)
#define LDS_BYTES 154752

extern __shared__ unsigned char smem[];

// load+pack 16 weight dwords into one 16-wide SSA vector; literal indices only.
#define LOADG16(V, RP, B) do {                                                  \
    float2 a0 = (RP)[(B)+0],  a1 = (RP)[(B)+1],  a2 = (RP)[(B)+2],  a3 = (RP)[(B)+3];   \
    float2 a4 = (RP)[(B)+4],  a5 = (RP)[(B)+5],  a6 = (RP)[(B)+6],  a7 = (RP)[(B)+7];   \
    float2 a8 = (RP)[(B)+8],  a9 = (RP)[(B)+9],  aA = (RP)[(B)+10], aB = (RP)[(B)+11];  \
    float2 aC = (RP)[(B)+12], aD = (RP)[(B)+13], aE = (RP)[(B)+14], aF = (RP)[(B)+15];  \
    V[0]  = pack2(a0.x, a0.y); V[1]  = pack2(a1.x, a1.y);                       \
    V[2]  = pack2(a2.x, a2.y); V[3]  = pack2(a3.x, a3.y);                       \
    V[4]  = pack2(a4.x, a4.y); V[5]  = pack2(a5.x, a5.y);                       \
    V[6]  = pack2(a6.x, a6.y); V[7]  = pack2(a7.x, a7.y);                       \
    V[8]  = pack2(a8.x, a8.y); V[9]  = pack2(a9.x, a9.y);                       \
    V[10] = pack2(aA.x, aA.y); V[11] = pack2(aB.x, aB.y);                       \
    V[12] = pack2(aC.x, aC.y); V[13] = pack2(aD.x, aD.y);                       \
    V[14] = pack2(aE.x, aE.y); V[15] = pack2(aF.x, aF.y);                       \
    __builtin_amdgcn_sched_barrier(0);                                          \
  } while (0)

// one j-block: consume prefetched (HC,OC), refill with j=JN, 16 dot2, fence.
#define JBLK(WIv, WFv, WGv, Q, HC, OC, PF, JN)                                  \
  { const uint4 hh = HC, wo = OC;                                               \
    if (PF) { HC = hq[JN]; OC = wo4r[(JN) * 1024]; }                            \
    ai = dot2f(WIv[4*(Q)+0], hh.x, ai); af = dot2f(WFv[4*(Q)+0], hh.x, af);     \
    ag = dot2f(WGv[4*(Q)+0], hh.x, ag); ao = dot2f(wo.x,         hh.x, ao);     \
    ai = dot2f(WIv[4*(Q)+1], hh.y, ai); af = dot2f(WFv[4*(Q)+1], hh.y, af);     \
    ag = dot2f(WGv[4*(Q)+1], hh.y, ag); ao = dot2f(wo.y,         hh.y, ao);     \
    ai = dot2f(WIv[4*(Q)+2], hh.z, ai); af = dot2f(WFv[4*(Q)+2], hh.z, af);     \
    ag = dot2f(WGv[4*(Q)+2], hh.z, ag); ao = dot2f(wo.z,         hh.z, ao);     \
    ai = dot2f(WIv[4*(Q)+3], hh.w, ai); af = dot2f(WFv[4*(Q)+3], hh.w, af);     \
    ag = dot2f(WGv[4*(Q)+3], hh.w, ag); ao = dot2f(wo.w,         hh.w, ao);     \
    __builtin_amdgcn_sched_barrier(0); }

__global__ __launch_bounds__(1024)
void lstm_seq_kernel(const float* __restrict__ touch, const float* __restrict__ gaze,
                     const float* __restrict__ l,
                     const float* __restrict__ tWih, const float* __restrict__ tWhh,
                     const float* __restrict__ tbih, const float* __restrict__ tbhh,
                     const float* __restrict__ gWih, const float* __restrict__ gWhh,
                     const float* __restrict__ gbih, const float* __restrict__ gbhh,
                     float* __restrict__ ws)
{
  const int bid  = (int)blockIdx.x;   // 0..63
  const int lsel = bid >> 5;          // 0 = touch, 1 = gaze
  const int b    = bid & 31;
  const int tid  = (int)threadIdx.x;  // 0..1023
  const int lane = tid & 63;
  const int wv   = tid >> 6;               // wave 0..15
  const int n    = wv * 16 + (lane >> 2);  // unit 0..255
  const int kq   = lane & 3;               // k-quarter 0..3 (lane bits 0-1)
  const int c0   = kq * 64;                // k-range start (64 fp16 per quarter)

  const float* __restrict__ x   = lsel ? gaze : touch;
  const float* __restrict__ Wih = lsel ? gWih : tWih;
  const float* __restrict__ Whh = lsel ? gWhh : tWhh;
  const float* __restrict__ bih = lsel ? gbih : tbih;
  const float* __restrict__ bhh = lsel ? gbhh : tbhh;
  const int D = lsel ? 4 : 3;

  uint4*         wo4  = (uint4*)(smem + WO_OFF);
  float4*        wihF = (float4*)(smem + WIH_OFF);
  float4*        biasF= (float4*)(smem + BIAS_OFF);
  unsigned char* cntL = smem + CNT_OFF;

  // ---- recurrent weights rows n(i), n+256(f), n+512(g), this thread's k-quarter:
  //      6 SSA vectors = 96 VGPRs
  u32x16 wi0, wi1, wf0, wf1, wg0, wg1;
  {
    const float2* ri = (const float2*)(Whh + (size_t)n * HDIM + c0);
    const float2* rf = (const float2*)(Whh + (size_t)(n + 256) * HDIM + c0);
    const float2* rg = (const float2*)(Whh + (size_t)(n + 512) * HDIM + c0);
    LOADG16(wi0, ri, 0);  LOADG16(wi1, ri, 16);
    LOADG16(wf0, rf, 0);  LOADG16(wf1, rf, 16);
    LOADG16(wg0, rg, 0);  LOADG16(wg1, rg, 16);
  }
  // ---- o-gate row n+768 (this k-quarter) -> LDS; step read = (j*1024+tid)*16B
  {
    const float2* ro = (const float2*)(Whh + (size_t)(n + 768) * HDIM + c0);
    #pragma unroll
    for (int j = 0; j < 8; ++j) {
      float2 e0 = ro[4*j], e1 = ro[4*j+1], e2 = ro[4*j+2], e3 = ro[4*j+3];
      uint4 v;
      v.x = pack2(e0.x, e0.y); v.y = pack2(e1.x, e1.y);
      v.z = pack2(e2.x, e2.y); v.w = pack2(e3.x, e3.y);
      wo4[j * 1024 + tid] = v;
      if ((j & 3) == 3) __builtin_amdgcn_sched_barrier(0);
    }
  }

  // ---- input-projection weights, fp32, padded to 4 cols (one row per thread)
  {
    const float* wr = Wih + (size_t)tid * D;
    float4 v;
    v.x = wr[0]; v.y = wr[1]; v.z = wr[2];
    v.w = (D == 4) ? wr[3] : 0.0f;
    wihF[tid] = v;
  }
  // ---- combined biases per unit, 4 gates
  if (tid < 256) {
    float4 v;
    v.x = bih[tid]       + bhh[tid];
    v.y = bih[tid + 256] + bhh[tid + 256];
    v.z = bih[tid + 512] + bhh[tid + 512];
    v.w = bih[tid + 768] + bhh[tid + 768];
    biasF[tid] = v;
  }
  __builtin_amdgcn_sched_barrier(0);

  // ---- glimpse-window cover counts
  {
    int s0 = (int)(l[b * MSZ + 0] * 2048.0f), s1 = (int)(l[b * MSZ + 1] * 2048.0f);
    int s2 = (int)(l[b * MSZ + 2] * 2048.0f), s3 = (int)(l[b * MSZ + 3] * 2048.0f);
    int s4 = (int)(l[b * MSZ + 4] * 2048.0f), s5 = (int)(l[b * MSZ + 5] * 2048.0f);
    int s6 = (int)(l[b * MSZ + 6] * 2048.0f), s7 = (int)(l[b * MSZ + 7] * 2048.0f);
    for (int t0 = tid; t0 < TLEN; t0 += 1024) {
      int c = 0;
      c += (t0 >= s0 && t0 < s0 + SELEN) ? 1 : 0;
      c += (t0 >= s1 && t0 < s1 + SELEN) ? 1 : 0;
      c += (t0 >= s2 && t0 < s2 + SELEN) ? 1 : 0;
      c += (t0 >= s3 && t0 < s3 + SELEN) ? 1 : 0;
      c += (t0 >= s4 && t0 < s4 + SELEN) ? 1 : 0;
      c += (t0 >= s5 && t0 < s5 + SELEN) ? 1 : 0;
      c += (t0 >= s6 && t0 < s6 + SELEN) ? 1 : 0;
      c += (t0 >= s7 && t0 < s7 + SELEN) ? 1 : 0;
      cntL[t0] = (unsigned char)c;
    }
  }

  if (tid < 144) ((unsigned int*)(smem + H2_OFF))[tid] = 0u;  // zero h buf0 (576 B)

  float cst = 0.f, Sall = 0.f, Swin = 0.f;
  const float* xrow = x + (size_t)b * TLEN * D;

  __syncthreads();

  const uint4* wo4r = wo4 + tid;
  const int hwr_base = (n >> 6) * 144 + (n & 63) * 2;  // byte offset of h[n] in a buf

  for (int t = 0; t < TLEN; ++t) {
    // block-uniform x_t / cnt_t -> scalars (SGPRs); latency hides under dots
    const float* xp = xrow + (size_t)t * D;
    const float x0 = uni(xp[0]), x1 = uni(xp[1]), x2 = uni(xp[2]);
    const float x3 = (D == 4) ? uni(xp[3]) : 0.0f;
    const float cw = (float)cntL[t];

    // this thread's h quarter (padded stride 144B -> conflict-free broadcast)
    const uint4* hq = (const uint4*)(smem + H2_OFF + (t & 1) * 576 + kq * 144);

    // depth-2 pipeline over 8 j-blocks
    uint4 hA = hq[0], oA = wo4r[0];
    uint4 hB = hq[1], oB = wo4r[1024];

    float ai = 0.f, af = 0.f, ag = 0.f, ao = 0.f;
    JBLK(wi0, wf0, wg0, 0, hA, oA, 1, 2)   // j=0
    JBLK(wi0, wf0, wg0, 1, hB, oB, 1, 3)   // j=1
    JBLK(wi0, wf0, wg0, 2, hA, oA, 1, 4)   // j=2
    JBLK(wi0, wf0, wg0, 3, hB, oB, 1, 5)   // j=3
    JBLK(wi1, wf1, wg1, 0, hA, oA, 1, 6)   // j=4
    JBLK(wi1, wf1, wg1, 1, hB, oB, 1, 7)   // j=5
    JBLK(wi1, wf1, wg1, 2, hA, oA, 0, 0)   // j=6
    JBLK(wi1, wf1, wg1, 3, hB, oB, 0, 0)   // j=7

    // combine the four k-quarters (kq = lane bits 0-1)
    ai += __shfl_xor(ai, 1); ai += __shfl_xor(ai, 2);
    af += __shfl_xor(af, 1); af += __shfl_xor(af, 2);
    ag += __shfl_xor(ag, 1); ag += __shfl_xor(ag, 2);
    ao += __shfl_xor(ao, 1); ao += __shfl_xor(ao, 2);

    __builtin_amdgcn_sched_barrier(0);

    // gates + state update (all 4 kq lanes compute identically)
    const float4 wr0 = wihF[n];
    const float4 wr1 = wihF[n + 256];
    const float4 wr2 = wihF[n + 512];
    const float4 wr3 = wihF[n + 768];
    const float4 bb  = biasF[n];
    const float gi = ai + bb.x + x0*wr0.x + x1*wr0.y + x2*wr0.z + x3*wr0.w;
    const float gf = af + bb.y + x0*wr1.x + x1*wr1.y + x2*wr1.z + x3*wr1.w;
    const float gg = ag + bb.z + x0*wr2.x + x1*wr2.y + x2*wr2.z + x3*wr2.w;
    const float go = ao + bb.w + x0*wr3.x + x1*wr3.y + x2*wr3.z + x3*wr3.w;
    const float si = sigm(gi), sf = sigm(gf), so = sigm(go);
    const float tg = tanh_f(gg);
    cst = sf * cst + si * tg;
    const float hv = so * tanh_f(cst);
    const float rh = fmaxf(hv, 0.0f);
    Sall += rh;
    Swin += cw * rh;

    if (kq == 0)
      *(_Float16*)(smem + H2_OFF + ((t + 1) & 1) * 576 + hwr_base) = (_Float16)hv;

    __syncthreads();
  }

  if (kq == 0) {
    ws[((0 * 2 + lsel) * 32 + b) * HDIM + n] = Sall;
    ws[((1 * 2 + lsel) * 32 + b) * HDIM + n] = Swin;
  }
}

__global__ void proj_kernel(const float* __restrict__ ws,
                            const float* __restrict__ tlw, const float* __restrict__ tlb,
                            const float* __restrict__ glw, const float* __restrict__ glb,
                            float* __restrict__ out)
{
  const int b    = (int)blockIdx.x >> 2;
  const int seg  = (int)blockIdx.x & 3;   // 0 t_mean, 1 t_attn, 2 g_mean, 3 g_attn
  const int j    = (int)threadIdx.x;
  const int lsel = seg >> 1;
  const int kind = seg & 1;
  const float* __restrict__ W    = lsel ? glw : tlw;
  const float* __restrict__ bias = lsel ? glb : tlb;
  const float scale = kind ? (1.0f / 512.0f) : (1.0f / 2048.0f);

  __shared__ float Sv[HDIM];
  Sv[j] = ws[((kind * 2 + lsel) * 32 + b) * HDIM + j] * scale;
  __syncthreads();

  float acc = bias[j];
  const float4* wr4 = (const float4*)(W + (size_t)j * HDIM);
  #pragma unroll 8
  for (int k4 = 0; k4 < HDIM / 4; ++k4) {
    const float4 w = wr4[k4];
    acc = fmaf(Sv[4*k4],     w.x, acc);
    acc = fmaf(Sv[4*k4 + 1], w.y, acc);
    acc = fmaf(Sv[4*k4 + 2], w.z, acc);
    acc = fmaf(Sv[4*k4 + 3], w.w, acc);
  }
  out[(size_t)b * 1024 + seg * HDIM + j] = acc;
}

extern "C" void kernel_launch(void* const* d_in, const int* in_sizes, int n_in,
                              void* d_out, int out_size, void* d_ws, size_t ws_size,
                              hipStream_t stream) {
  (void)in_sizes; (void)n_in; (void)out_size; (void)ws_size;
  const float* touch = (const float*)d_in[0];
  const float* gaze  = (const float*)d_in[1];
  const float* l     = (const float*)d_in[2];
  const float* tWih  = (const float*)d_in[3];
  const float* tWhh  = (const float*)d_in[4];
  const float* tbih  = (const float*)d_in[5];
  const float* tbhh  = (const float*)d_in[6];
  const float* gWih  = (const float*)d_in[7];
  const float* gWhh  = (const float*)d_in[8];
  const float* gbih  = (const float*)d_in[9];
  const float* gbhh  = (const float*)d_in[10];
  const float* tlw   = (const float*)d_in[11];
  const float* tlb   = (const float*)d_in[12];
  const float* glw   = (const float*)d_in[13];
  const float* glb   = (const float*)d_in[14];
  float* out = (float*)d_out;
  float* ws  = (float*)d_ws;

  hipFuncSetAttribute(reinterpret_cast<const void*>(&lstm_seq_kernel),
                      hipFuncAttributeMaxDynamicSharedMemorySize, LDS_BYTES);

  hipLaunchKernelGGL(lstm_seq_kernel, dim3(64), dim3(1024), LDS_BYTES, stream,
                     touch, gaze, l, tWih, tWhh, tbih, tbhh,
                     gWih, gWhh, gbih, gbhh, ws);
  hipLaunchKernelGGL(proj_kernel, dim3(128), dim3(256), 0, stream,
                     ws, tlw, tlb, glw, glb, out);
}

// Round 8
// 3469.455 us; speedup vs baseline: 1.5418x; 1.5418x over previous
//
#include <hip/hip_runtime.h>

#define HDIM 256
#define TLEN 2048
#define SELEN 64
#define MSZ 8

typedef _Float16 f16x2 __attribute__((ext_vector_type(2)));
typedef unsigned int u32x16 __attribute__((ext_vector_type(16)));

__device__ __forceinline__ float dot2f(unsigned int w, unsigned int h, float acc) {
  return __builtin_amdgcn_fdot2(__builtin_bit_cast(f16x2, w),
                                __builtin_bit_cast(f16x2, h), acc, false);
}

__device__ __forceinline__ unsigned int pack2(float a, float b) {
  f16x2 v;
  v.x = (_Float16)a; v.y = (_Float16)b;
  return __builtin_bit_cast(unsigned int, v);
}

__device__ __forceinline__ float sigm(float x)   { return 1.0f / (1.0f + __expf(-x)); }
__device__ __forceinline__ float tanh_f(float x) { return 1.0f - 2.0f / (__expf(2.0f * x) + 1.0f); }

// LDS layout (bytes) — STATIC shared: size must be visible to the compiler so
// its occupancy model knows only ONE 512-thread block fits a CU -> 2 waves/SIMD
// -> 256-VGPR budget. (Rounds 1-7: dynamic LDS hid this; compiler assumed
// 2 blocks/CU, capped VGPRs at 128, spilled the 192-dword weight set: ~25 MB
// WRITE_SIZE and a stable 3.5 ms.)
#define WO_OFF    0        // 512 thr * 16 uint4   = 131072 B (o-gate fp16x2 weights)
#define WIH_OFF   131072   // 1024 rows * float4   = 16384 B  (input-proj weights, padded)
#define CNT_OFF   147456   // 2048 * u8            = 2048 B   (window cover counts)
#define H2_OFF    149504   // 2 bufs * 256 fp16    = 1024 B   (h double-buffered)
#define LDS_BYTES 150528   // 147 KB < 160 KB gfx950 addressable LDS

__shared__ __align__(16) unsigned char smem[LDS_BYTES];

// load+pack 16 weight dwords into one 16-wide SSA vector; literal indices only.
#define LOADG16(V, RP, B) do {                                                  \
    float2 a0 = (RP)[(B)+0],  a1 = (RP)[(B)+1],  a2 = (RP)[(B)+2],  a3 = (RP)[(B)+3];   \
    float2 a4 = (RP)[(B)+4],  a5 = (RP)[(B)+5],  a6 = (RP)[(B)+6],  a7 = (RP)[(B)+7];   \
    float2 a8 = (RP)[(B)+8],  a9 = (RP)[(B)+9],  aA = (RP)[(B)+10], aB = (RP)[(B)+11];  \
    float2 aC = (RP)[(B)+12], aD = (RP)[(B)+13], aE = (RP)[(B)+14], aF = (RP)[(B)+15];  \
    V[0]  = pack2(a0.x, a0.y); V[1]  = pack2(a1.x, a1.y);                       \
    V[2]  = pack2(a2.x, a2.y); V[3]  = pack2(a3.x, a3.y);                       \
    V[4]  = pack2(a4.x, a4.y); V[5]  = pack2(a5.x, a5.y);                       \
    V[6]  = pack2(a6.x, a6.y); V[7]  = pack2(a7.x, a7.y);                       \
    V[8]  = pack2(a8.x, a8.y); V[9]  = pack2(a9.x, a9.y);                       \
    V[10] = pack2(aA.x, aA.y); V[11] = pack2(aB.x, aB.y);                       \
    V[12] = pack2(aC.x, aC.y); V[13] = pack2(aD.x, aD.y);                       \
    V[14] = pack2(aE.x, aE.y); V[15] = pack2(aF.x, aF.y);                       \
    __builtin_amdgcn_sched_barrier(0);                                          \
  } while (0)

// one j-block of the step: use prefetched (HC,OC), refill the slot with j=JN,
// run 16 dot2, then fence -> in-flight LDS results capped at 2 slots (16 VGPRs)
#define JBLK(WIv, WFv, WGv, Q, HC, OC, PF, JN)                                  \
  { const uint4 hh = HC, wo = OC;                                               \
    if (PF) { HC = hv4[JN]; OC = wo4r[(JN) * 512]; }                            \
    ai = dot2f(WIv[4*(Q)+0], hh.x, ai); af = dot2f(WFv[4*(Q)+0], hh.x, af);     \
    ag = dot2f(WGv[4*(Q)+0], hh.x, ag); ao = dot2f(wo.x,         hh.x, ao);     \
    ai = dot2f(WIv[4*(Q)+1], hh.y, ai); af = dot2f(WFv[4*(Q)+1], hh.y, af);     \
    ag = dot2f(WGv[4*(Q)+1], hh.y, ag); ao = dot2f(wo.y,         hh.y, ao);     \
    ai = dot2f(WIv[4*(Q)+2], hh.z, ai); af = dot2f(WFv[4*(Q)+2], hh.z, af);     \
    ag = dot2f(WGv[4*(Q)+2], hh.z, ag); ao = dot2f(wo.z,         hh.z, ao);     \
    ai = dot2f(WIv[4*(Q)+3], hh.w, ai); af = dot2f(WFv[4*(Q)+3], hh.w, af);     \
    ag = dot2f(WGv[4*(Q)+3], hh.w, ag); ao = dot2f(wo.w,         hh.w, ao);     \
    __builtin_amdgcn_sched_barrier(0); }

__global__ void
__attribute__((amdgpu_flat_work_group_size(512, 512), amdgpu_waves_per_eu(2, 2)))
lstm_seq_kernel(const float* __restrict__ touch, const float* __restrict__ gaze,
                const float* __restrict__ l,
                const float* __restrict__ tWih, const float* __restrict__ tWhh,
                const float* __restrict__ tbih, const float* __restrict__ tbhh,
                const float* __restrict__ gWih, const float* __restrict__ gWhh,
                const float* __restrict__ gbih, const float* __restrict__ gbhh,
                float* __restrict__ ws)
{
  const int bid  = (int)blockIdx.x;   // 0..63
  const int lsel = bid >> 5;          // 0 = touch, 1 = gaze
  const int b    = bid & 31;
  const int tid  = (int)threadIdx.x;  // 0..511
  const int lane = tid & 63;
  const int wv   = tid >> 6;          // wave 0..7
  const int n    = wv * 32 + (lane & 31);  // unit 0..255
  const int kh   = lane >> 5;              // k-half 0/1
  const int c0   = kh * 128;               // k-range start

  const float* __restrict__ x   = lsel ? gaze : touch;
  const float* __restrict__ Wih = lsel ? gWih : tWih;
  const float* __restrict__ Whh = lsel ? gWhh : tWhh;
  const float* __restrict__ bih = lsel ? gbih : tbih;
  const float* __restrict__ bhh = lsel ? gbhh : tbhh;
  const int D = lsel ? 4 : 3;

  unsigned int*  woL  = (unsigned int*)(smem + WO_OFF);
  float4*        wihF = (float4*)(smem + WIH_OFF);
  unsigned char* cntL = smem + CNT_OFF;

  // ---- recurrent weights rows n(i), n+256(f), n+512(g): 12 SSA vectors = 192 VGPRs
  u32x16 wi0, wi1, wi2, wi3, wf0, wf1, wf2, wf3, wg0, wg1, wg2, wg3;
  {
    const float2* ri = (const float2*)(Whh + (size_t)n * HDIM + c0);
    const float2* rf = (const float2*)(Whh + (size_t)(n + 256) * HDIM + c0);
    const float2* rg = (const float2*)(Whh + (size_t)(n + 512) * HDIM + c0);
    LOADG16(wi0, ri, 0);  LOADG16(wi1, ri, 16);  LOADG16(wi2, ri, 32);  LOADG16(wi3, ri, 48);
    LOADG16(wf0, rf, 0);  LOADG16(wf1, rf, 16);  LOADG16(wf2, rf, 32);  LOADG16(wf3, rf, 48);
    LOADG16(wg0, rg, 0);  LOADG16(wg1, rg, 16);  LOADG16(wg2, rg, 32);  LOADG16(wg3, rg, 48);
  }
  // ---- o-gate row n+768 -> LDS, laid out so step-read is (j*512+tid)*16B
  {
    const float2* ro = (const float2*)(Whh + (size_t)(n + 768) * HDIM + c0);
    uint4* wo4 = (uint4*)woL;
    #pragma unroll
    for (int jb = 0; jb < 4; ++jb) {
      #pragma unroll
      for (int q = 0; q < 4; ++q) {
        const int j = jb * 4 + q;
        float2 e0 = ro[4*j], e1 = ro[4*j+1], e2 = ro[4*j+2], e3 = ro[4*j+3];
        uint4 v;
        v.x = pack2(e0.x, e0.y); v.y = pack2(e1.x, e1.y);
        v.z = pack2(e2.x, e2.y); v.w = pack2(e3.x, e3.y);
        wo4[j * 512 + tid] = v;
      }
      __builtin_amdgcn_sched_barrier(0);
    }
  }

  // ---- input-projection weights, fp32, padded to 4 cols
  for (int r = tid; r < 1024; r += 512) {
    const float* wr = Wih + (size_t)r * D;
    float4 v;
    v.x = wr[0]; v.y = wr[1]; v.z = wr[2];
    v.w = (D == 4) ? wr[3] : 0.0f;
    wihF[r] = v;
  }
  __builtin_amdgcn_sched_barrier(0);

  // ---- glimpse-window cover counts
  {
    int s0 = (int)(l[b * MSZ + 0] * 2048.0f), s1 = (int)(l[b * MSZ + 1] * 2048.0f);
    int s2 = (int)(l[b * MSZ + 2] * 2048.0f), s3 = (int)(l[b * MSZ + 3] * 2048.0f);
    int s4 = (int)(l[b * MSZ + 4] * 2048.0f), s5 = (int)(l[b * MSZ + 5] * 2048.0f);
    int s6 = (int)(l[b * MSZ + 6] * 2048.0f), s7 = (int)(l[b * MSZ + 7] * 2048.0f);
    for (int t0 = tid; t0 < TLEN; t0 += 512) {
      int c = 0;
      c += (t0 >= s0 && t0 < s0 + SELEN) ? 1 : 0;
      c += (t0 >= s1 && t0 < s1 + SELEN) ? 1 : 0;
      c += (t0 >= s2 && t0 < s2 + SELEN) ? 1 : 0;
      c += (t0 >= s3 && t0 < s3 + SELEN) ? 1 : 0;
      c += (t0 >= s4 && t0 < s4 + SELEN) ? 1 : 0;
      c += (t0 >= s5 && t0 < s5 + SELEN) ? 1 : 0;
      c += (t0 >= s6 && t0 < s6 + SELEN) ? 1 : 0;
      c += (t0 >= s7 && t0 < s7 + SELEN) ? 1 : 0;
      cntL[t0] = (unsigned char)c;
    }
  }

  if (tid < 128) ((unsigned int*)(smem + H2_OFF))[tid] = 0u;  // zero buf0

  const float bi_ = bih[n]       + bhh[n];
  const float bf_ = bih[n + 256] + bhh[n + 256];
  const float bg_ = bih[n + 512] + bhh[n + 512];
  const float bo_ = bih[n + 768] + bhh[n + 768];

  float cst = 0.f, Sall = 0.f, Swin = 0.f;
  const float* xrow = x + (size_t)b * TLEN * D;

  // prologue: x_0 in registers
  float x0 = xrow[0], x1 = xrow[1], x2 = xrow[2];
  float x3 = (D == 4) ? xrow[3] : 0.0f;

  __syncthreads();

  float cw = (float)cntL[0];
  const uint4* wo4r = ((const uint4*)woL) + tid;

  for (int t = 0; t < TLEN; ++t) {
    // next-step x/cnt loads issued early; consumed after the dot chain
    const int tn = (t + 1 < TLEN) ? (t + 1) : t;
    const float* xp = xrow + (size_t)tn * D;
    const float nx0 = xp[0], nx1 = xp[1], nx2 = xp[2];
    const float nx3 = (D == 4) ? xp[3] : 0.0f;
    const float ncw = (float)cntL[tn];

    const uint4* hv4 = (const uint4*)(smem + H2_OFF + (t & 1) * 512 + kh * 256);

    // depth-2 pipeline prologue
    uint4 hA = hv4[0], oA = wo4r[0];
    uint4 hB = hv4[1], oB = wo4r[512];

    float ai = 0.f, af = 0.f, ag = 0.f, ao = 0.f;
    JBLK(wi0, wf0, wg0, 0, hA, oA, 1,  2)   // j=0
    JBLK(wi0, wf0, wg0, 1, hB, oB, 1,  3)   // j=1
    JBLK(wi0, wf0, wg0, 2, hA, oA, 1,  4)   // j=2
    JBLK(wi0, wf0, wg0, 3, hB, oB, 1,  5)   // j=3
    JBLK(wi1, wf1, wg1, 0, hA, oA, 1,  6)   // j=4
    JBLK(wi1, wf1, wg1, 1, hB, oB, 1,  7)   // j=5
    JBLK(wi1, wf1, wg1, 2, hA, oA, 1,  8)   // j=6
    JBLK(wi1, wf1, wg1, 3, hB, oB, 1,  9)   // j=7
    JBLK(wi2, wf2, wg2, 0, hA, oA, 1, 10)   // j=8
    JBLK(wi2, wf2, wg2, 1, hB, oB, 1, 11)   // j=9
    JBLK(wi2, wf2, wg2, 2, hA, oA, 1, 12)   // j=10
    JBLK(wi2, wf2, wg2, 3, hB, oB, 1, 13)   // j=11
    JBLK(wi3, wf3, wg3, 0, hA, oA, 1, 14)   // j=12
    JBLK(wi3, wf3, wg3, 1, hB, oB, 1, 15)   // j=13
    JBLK(wi3, wf3, wg3, 2, hA, oA, 0,  0)   // j=14
    JBLK(wi3, wf3, wg3, 3, hB, oB, 0,  0)   // j=15

    // combine the two k-halves within the wave
    ai += __shfl_xor(ai, 32);
    af += __shfl_xor(af, 32);
    ag += __shfl_xor(ag, 32);
    ao += __shfl_xor(ao, 32);

    // gates + state update (both k-half lanes compute identically)
    const float4 wr0 = wihF[n];
    const float4 wr1 = wihF[n + 256];
    const float4 wr2 = wihF[n + 512];
    const float4 wr3 = wihF[n + 768];
    const float gi = ai + bi_ + x0*wr0.x + x1*wr0.y + x2*wr0.z + x3*wr0.w;
    const float gf = af + bf_ + x0*wr1.x + x1*wr1.y + x2*wr1.z + x3*wr1.w;
    const float gg = ag + bg_ + x0*wr2.x + x1*wr2.y + x2*wr2.z + x3*wr2.w;
    const float go = ao + bo_ + x0*wr3.x + x1*wr3.y + x2*wr3.z + x3*wr3.w;
    const float si = sigm(gi), sf = sigm(gf), so = sigm(go);
    const float tg = tanh_f(gg);
    cst = sf * cst + si * tg;
    const float hv = so * tanh_f(cst);
    const float rh = fmaxf(hv, 0.0f);
    Sall += rh;
    Swin += cw * rh;

    if (kh == 0)
      ((_Float16*)(smem + H2_OFF + ((t + 1) & 1) * 512))[n] = (_Float16)hv;

    x0 = nx0; x1 = nx1; x2 = nx2; x3 = nx3; cw = ncw;

    __syncthreads();
  }

  if (kh == 0) {
    ws[((0 * 2 + lsel) * 32 + b) * HDIM + n] = Sall;
    ws[((1 * 2 + lsel) * 32 + b) * HDIM + n] = Swin;
  }
}

__global__ void proj_kernel(const float* __restrict__ ws,
                            const float* __restrict__ tlw, const float* __restrict__ tlb,
                            const float* __restrict__ glw, const float* __restrict__ glb,
                            float* __restrict__ out)
{
  const int b    = (int)blockIdx.x >> 2;
  const int seg  = (int)blockIdx.x & 3;   // 0 t_mean, 1 t_attn, 2 g_mean, 3 g_attn
  const int j    = (int)threadIdx.x;
  const int lsel = seg >> 1;
  const int kind = seg & 1;
  const float* __restrict__ W    = lsel ? glw : tlw;
  const float* __restrict__ bias = lsel ? glb : tlb;
  const float scale = kind ? (1.0f / 512.0f) : (1.0f / 2048.0f);

  __shared__ float Sv[HDIM];
  Sv[j] = ws[((kind * 2 + lsel) * 32 + b) * HDIM + j] * scale;
  __syncthreads();

  float acc = bias[j];
  const float4* wr4 = (const float4*)(W + (size_t)j * HDIM);
  #pragma unroll 8
  for (int k4 = 0; k4 < HDIM / 4; ++k4) {
    const float4 w = wr4[k4];
    acc = fmaf(Sv[4*k4],     w.x, acc);
    acc = fmaf(Sv[4*k4 + 1], w.y, acc);
    acc = fmaf(Sv[4*k4 + 2], w.z, acc);
    acc = fmaf(Sv[4*k4 + 3], w.w, acc);
  }
  out[(size_t)b * 1024 + seg * HDIM + j] = acc;
}

extern "C" void kernel_launch(void* const* d_in, const int* in_sizes, int n_in,
                              void* d_out, int out_size, void* d_ws, size_t ws_size,
                              hipStream_t stream) {
  (void)in_sizes; (void)n_in; (void)out_size; (void)ws_size;
  const float* touch = (const float*)d_in[0];
  const float* gaze  = (const float*)d_in[1];
  const float* l     = (const float*)d_in[2];
  const float* tWih  = (const float*)d_in[3];
  const float* tWhh  = (const float*)d_in[4];
  const float* tbih  = (const float*)d_in[5];
  const float* tbhh  = (const float*)d_in[6];
  const float* gWih  = (const float*)d_in[7];
  const float* gWhh  = (const float*)d_in[8];
  const float* gbih  = (const float*)d_in[9];
  const float* gbhh  = (const float*)d_in[10];
  const float* tlw   = (const float*)d_in[11];
  const float* tlb   = (const float*)d_in[12];
  const float* glw   = (const float*)d_in[13];
  const float* glb   = (const float*)d_in[14];
  float* out = (float*)d_out;
  float* ws  = (float*)d_ws;

  hipLaunchKernelGGL(lstm_seq_kernel, dim3(64), dim3(512), 0, stream,
                     touch, gaze, l, tWih, tWhh, tbih, tbhh,
                     gWih, gWhh, gbih, gbhh, ws);
  hipLaunchKernelGGL(proj_kernel, dim3(128), dim3(256), 0, stream,
                     ws, tlw, tlb, glw, glb, out);
}